// Round 1
// baseline (415.809 us; speedup 1.0000x reference)
//
#include <hip/hip_runtime.h>
#include <math.h>

typedef unsigned short u16;
typedef unsigned int u32;
typedef __attribute__((ext_vector_type(4))) float f4;
typedef __attribute__((ext_vector_type(2))) float f2;
typedef __attribute__((ext_vector_type(4))) u16 u16x4;
typedef __attribute__((ext_vector_type(8))) u16 u16x8;
typedef __attribute__((ext_vector_type(8))) short bf8;

#define N_IMG 8
#define HS 128               // half spatial
#define NPOS (N_IMG*HS*HS)   // 131072
#define IN_CH 192
#define HID_CH 384

__device__ __forceinline__ u16 f2bf(float f) {
  union { float f; u32 u; } v; v.f = f;
  u32 r = v.u + 0x7FFFu + ((v.u >> 16) & 1u);
  return (u16)(r >> 16);
}
__device__ __forceinline__ float bf2f(u16 u) {
  union { u32 u; float f; } v; v.u = ((u32)u) << 16; return v.f;
}
// f2 pair from one dword holding two bf16 (even=low half, odd=high half)
__device__ __forceinline__ f2 bfpair(u32 d) {
  union { u32 u; float f; } lo, hi;
  lo.u = d << 16; hi.u = d & 0xffff0000u;
  f2 r; r[0] = lo.f; r[1] = hi.f; return r;
}
// gelu(x) = x * sigmoid(1.595769122x + 0.071354816x^3)  (tanh-form, exact identity)
// = x * rcp(1 + exp2(x*(-2.302208 - 0.102942*x^2)))
__device__ __forceinline__ float gelu_fast(float x) {
  float x2 = x * x;
  float z = x * (-2.302208f - 0.102942f * x2);
  float e = __builtin_amdgcn_exp2f(z);
  return x * __builtin_amdgcn_rcpf(1.0f + e);
}
__device__ __forceinline__ void gl_lds16(const u16* g, u16* l) {
  __builtin_amdgcn_global_load_lds(
      (__attribute__((address_space(1))) void*)(u16*)g,
      (__attribute__((address_space(3))) void*)l, 16, 0, 0);
}

// ---------------- K0: zero stats ----------------
__global__ void k0_zero(float* stats) { stats[threadIdx.x] = 0.0f; }

// ---------------- K1: DWT (interleaved-band semantics) ----------------
__global__ __launch_bounds__(256) void k1_dwt(
    const float* __restrict__ x,   // [8][256][256][64]
    u16* __restrict__ high,        // [NPOS][192]
    float* __restrict__ out,       // [8][256][256][64]
    float* __restrict__ stats)     // sum[192], sq[192]
{
  const int blk = blockIdx.x;         // b*128 + i
  const int b = blk >> 7, i = blk & 127;
  const int t = threadIdx.x;
  const int c4 = t & 15;              // input channels c4*4 .. c4*4+3
  const int j0 = t >> 4;              // 0..15
  const int rowE = ((b * 256 + 2 * i) * 256) * 64;
  const int rowO = rowE + 256 * 64;
  const bool isHigh = (c4 >= 4);

  float sacc[16], qacc[16];
#pragma unroll
  for (int v = 0; v < 16; v++) { sacc[v] = 0.f; qacc[v] = 0.f; }

  for (int iter = 0; iter < 8; ++iter) {
    const int j = j0 + 16 * iter;
    const int colE = (2 * j) * 64 + c4 * 4;
    f4 va = *(const f4*)(x + rowE + colE);
    f4 vb = *(const f4*)(x + rowE + colE + 64);
    f4 vc = *(const f4*)(x + rowO + colE);
    f4 vd = *(const f4*)(x + rowO + colE + 64);
    f4 sb0 = (va + vb + vc + vd) * 0.5f;  // LL
    f4 sb1 = (va - vb + vc - vd) * 0.5f;  // LH
    f4 sb2 = (va + vb - vc - vd) * 0.5f;  // HL
    f4 sb3 = (va - vb - vc + vd) * 0.5f;  // HH

    if (!isHigh) {
      float* dst = out + rowE + (2 * j) * 64 + 16 * c4;
#pragma unroll
      for (int cc = 0; cc < 4; cc++) {
        f4 ov;
        ov[0] = sb0[cc]; ov[1] = sb1[cc]; ov[2] = sb2[cc]; ov[3] = sb3[cc];
        ((f4*)dst)[cc] = ov;
      }
    } else {
      const int n = b * 16384 + i * 128 + j;
      u16* dst = high + n * 192 + 16 * (c4 - 4);
#pragma unroll
      for (int half = 0; half < 2; half++) {
        u16x8 pk;
#pragma unroll
        for (int cc2 = 0; cc2 < 2; cc2++) {
          const int cc = half * 2 + cc2;
          pk[cc2 * 4 + 0] = f2bf(sb0[cc]);
          pk[cc2 * 4 + 1] = f2bf(sb1[cc]);
          pk[cc2 * 4 + 2] = f2bf(sb2[cc]);
          pk[cc2 * 4 + 3] = f2bf(sb3[cc]);
        }
        *(u16x8*)(dst + half * 8) = pk;
      }
#pragma unroll
      for (int cc = 0; cc < 4; cc++) {
        float e0 = sb0[cc], e1 = sb1[cc], e2 = sb2[cc], e3 = sb3[cc];
        sacc[cc * 4 + 0] += e0; qacc[cc * 4 + 0] += e0 * e0;
        sacc[cc * 4 + 1] += e1; qacc[cc * 4 + 1] += e1 * e1;
        sacc[cc * 4 + 2] += e2; qacc[cc * 4 + 2] += e2 * e2;
        sacc[cc * 4 + 3] += e3; qacc[cc * 4 + 3] += e3 * e3;
      }
    }
  }

  float vals[32];
#pragma unroll
  for (int v = 0; v < 16; v++) { vals[v] = sacc[v]; vals[16 + v] = qacc[v]; }
#pragma unroll
  for (int v = 0; v < 32; v++) {
    float xx = vals[v];
    xx += __shfl_down(xx, 32);
    xx += __shfl_down(xx, 16);
    vals[v] = xx;
  }
  __shared__ float sred[4][12][32];
  const int lane = t & 63, wave = t >> 6;
  if (lane >= 4 && lane < 16) {
#pragma unroll
    for (int v = 0; v < 32; v++) sred[wave][lane - 4][v] = vals[v];
  }
  __syncthreads();
  if (t < 192) {
    const int g = t >> 4, L = t & 15;
    float s = sred[0][g][L] + sred[1][g][L] + sred[2][g][L] + sred[3][g][L];
    float q = sred[0][g][16 + L] + sred[1][g][16 + L] + sred[2][g][16 + L] + sred[3][g][16 + L];
    atomicAdd(&stats[t], s);
    atomicAdd(&stats[192 + t], q);
  }
}

// ---------------- K2a: BN scale/shift ----------------
__global__ void k2a(const float* __restrict__ stats, const float* __restrict__ gamma,
                    const float* __restrict__ beta, float* __restrict__ st)
{
  const int t = threadIdx.x;
  if (t < 192) {
    const float inv_n = 1.0f / 131072.0f;
    float mean = stats[t] * inv_n;
    float var = stats[192 + t] * inv_n - mean * mean;
    var = fmaxf(var, 0.0f);
    float s = gamma[t] * rsqrtf(var + 1e-5f);
    st[t] = s;
    st[192 + t] = beta[t] - mean * s;
  }
}

// ---------------- K2b: fold weights ----------------
__global__ __launch_bounds__(64) void k2b(
    const float* __restrict__ w_in, const float* __restrict__ w_out,
    const float* __restrict__ st, const float* __restrict__ res_scale,
    u16* __restrict__ w_in_f, float* __restrict__ bias1, u16* __restrict__ w_out_f)
{
  const int o = blockIdx.x, lane = threadIdx.x;
  if (o < 384) {
    float p = 0.f;
    for (int c = lane; c < 192; c += 64) {
      float w = w_in[o * 192 + c];
      w_in_f[o * 192 + c] = f2bf(w * st[c]);
      p += w * st[192 + c];
    }
#pragma unroll
    for (int off = 32; off; off >>= 1) p += __shfl_down(p, off);
    if (lane == 0) bias1[o] = p;
  } else {
    const int o2 = o - 384;
    const float rs = res_scale[0];
    for (int c = lane; c < 384; c += 64)
      w_out_f[o2 * 384 + c] = f2bf(w_out[o2 * 384 + c] * rs);
  }
}

// ---------------- K3: GEMM1  h1 = high @ w_in_f^T + bias ----------------
// h1 layout: [2][Mg][192] (channel halves split)
// Epilogue v2: stage C tile in LDS (u16[128][136], stride 68 dw -> conflict-free),
// then cooperative u16x8 stores (256 B contiguous per row-segment).
__global__ __launch_bounds__(256) void k3_gemm1(
    const u16* __restrict__ A,   // [Mg][192] bf16
    const u16* __restrict__ Bw,  // [384][192] bf16
    const float* __restrict__ bias,
    u16* __restrict__ C,         // [2][Mg][192] bf16
    int Mg)
{
  __shared__ __align__(16) u16 smem[128 * 136];   // 34816 B; As/Bs overlap front
  u16* As = smem;                 // 128*32 u16
  u16* Bs = smem + 128 * 32;      // 128*32 u16
  const int t = threadIdx.x;
  const int lane = t & 63, wave = t >> 6;
  const int wm = wave >> 1, wn = wave & 1;
  const int m0 = blockIdx.x * 128;
  const int n0 = blockIdx.y * 128;
  const int lrow = lane >> 2, lcol = lane & 3;
  const int frow = lane & 15, fk = (lane >> 4) * 8;

  f4 acc[4][4];
#pragma unroll
  for (int a = 0; a < 4; a++)
#pragma unroll
    for (int b = 0; b < 4; b++) acc[a][b] = 0.0f;

  for (int ks = 0; ks < 6; ++ks) {
    const int kb = ks * 32;
#pragma unroll
    for (int l = 0; l < 2; ++l) {
      const int r = wave * 32 + l * 16 + lrow;
      gl_lds16(A + (size_t)(m0 + r) * 192 + kb + lcol * 8, As + (wave * 32 + l * 16) * 32);
      gl_lds16(Bw + (size_t)(n0 + r) * 192 + kb + lcol * 8, Bs + (wave * 32 + l * 16) * 32);
    }
    __syncthreads();
    bf8 af[4], bfr[4];
#pragma unroll
    for (int fm = 0; fm < 4; ++fm)
      af[fm] = *(const bf8*)(As + (wm * 64 + fm * 16 + frow) * 32 + fk);
#pragma unroll
    for (int fn = 0; fn < 4; ++fn)
      bfr[fn] = *(const bf8*)(Bs + (wn * 64 + fn * 16 + frow) * 32 + fk);
#pragma unroll
    for (int fm = 0; fm < 4; ++fm)
#pragma unroll
      for (int fn = 0; fn < 4; ++fn)
        acc[fm][fn] = __builtin_amdgcn_mfma_f32_16x16x32_bf16(af[fm], bfr[fn], acc[fm][fn], 0, 0, 0);
    __syncthreads();
  }

  // -- stage acc -> LDS (bias folded, bf16) --
  u16* Ct = smem;                         // [128][136]
  const int r0 = (lane >> 4) * 4, cc = lane & 15;
#pragma unroll
  for (int fn = 0; fn < 4; ++fn) {
    const int ncol = wn * 64 + fn * 16 + cc;
    const float bv = bias[n0 + ncol];
#pragma unroll
    for (int fm = 0; fm < 4; ++fm) {
      const int mr = wm * 64 + fm * 16 + r0;
#pragma unroll
      for (int r = 0; r < 4; ++r)
        Ct[(mr + r) * 136 + ncol] = f2bf(acc[fm][fn][r] + bv);
    }
  }
  __syncthreads();
  // -- cooperative vector store: 128 rows x 16 segs of 8 ch --
#pragma unroll
  for (int it = 0; it < 8; ++it) {
    const int idx = it * 256 + t;
    const int row = idx >> 4, seg = idx & 15;
    const int col = n0 + seg * 8;
    const int hsel = (col >= 192) ? 1 : 0;
    u16x8 v = *(const u16x8*)(Ct + row * 136 + seg * 8);
    *(u16x8*)(C + (size_t)hsel * Mg * 192 + (size_t)(m0 + row) * 192 + (col - hsel * 192)) = v;
  }
}

// ---------------- K4 v3: depthwise 3x3 + GELU, single-barrier LDS tile ----------------
// h1/h2 layout [2][Mg][192]. Block: 192 thr = 24 ch-octets x 8 j. Tile: 8 rows x 8 j x 192ch(half).
// DMA whole 10-row halo tile to LDS (40 wave-issues), ONE barrier, then pure-LDS compute.
__global__ __launch_bounds__(192) void k4_dw(
    const u16* __restrict__ h1,    // [2][Mg][192]
    const float* __restrict__ wdw, // [384*9]
    u16* __restrict__ h2,          // [2][Mg][192]
    int Mg)
{
  const int bx = blockIdx.x;
  const int half = bx & 1;
  const int jt = (bx >> 1) & 15;
  const int rt = (bx >> 5) & 15;
  const int img = bx >> 9;
  const int t = threadIdx.x;
  const int lane = t & 63, wave = t >> 6;
  const int ibase = img * 16384;
  const int r0 = rt * 8;
  const int jBase = (jt == 0) ? 0 : (jt * 8 - 1);
  const int jOff = (jt == 0) ? 0 : 1;
  const size_t hs = (size_t)half * Mg * 192;
  const u16* src = h1 + hs;
  u16* dst = h2 + hs;

  __shared__ u16 lds[10 * 2048];   // [row 0..9][2048 u16 = 10.67 j * 192ch]

  // bulk DMA: 10 rows x 4 segs of 1024 B
  for (int i = wave; i < 40; i += 3) {
    const int r = i >> 2, seg = i & 3;
    const int gr = r0 - 1 + r;
    if (gr >= 0 && gr < 128) {
      const u16* g = src + (size_t)(ibase + gr * 128 + jBase) * 192 + seg * 512 + lane * 8;
      gl_lds16(g, &lds[r * 2048 + seg * 512]);
    }
  }
  if (rt == 0) {
    for (int c = t; c < 256; c += 192) *(u16x8*)&lds[c * 8] = (u16x8)(0);
  }
  if (rt == 15) {
    for (int c = t; c < 256; c += 192) *(u16x8*)&lds[9 * 2048 + c * 8] = (u16x8)(0);
  }
  __syncthreads();   // the ONLY barrier

  const int o = t % 24, jl = t / 24;
  const int jg = jt * 8 + jl;
  const int cl = o * 8;             // channel offset within half
  const int cg = half * 192 + cl;   // global channel

  f2 w2[3][3][4];
#pragma unroll
  for (int dy = 0; dy < 3; dy++)
#pragma unroll
    for (int dx = 0; dx < 3; dx++)
#pragma unroll
      for (int p = 0; p < 4; p++) {
        w2[dy][dx][p][0] = wdw[(cg + 2 * p) * 9 + dy * 3 + dx];
        w2[dy][dx][p][1] = wdw[(cg + 2 * p + 1) * 9 + dy * 3 + dx];
      }

  int im = jl - 1 + jOff; if (im < 0) im = 0;
  const int i0 = jl + jOff, ip = jl + 1 + jOff;

  f2 accA[4], accB[4];
#pragma unroll
  for (int p = 0; p < 4; p++) { accA[p] = (f2)(0.f); accB[p] = (f2)(0.f); }

#pragma unroll
  for (int r = 0; r < 10; ++r) {
    u16x8 vm = *(const u16x8*)&lds[r * 2048 + im * 192 + cl];
    u16x8 v0 = *(const u16x8*)&lds[r * 2048 + i0 * 192 + cl];
    u16x8 vp = *(const u16x8*)&lds[r * 2048 + ip * 192 + cl];
    if (jg == 0)   vm = (u16x8)(0);
    if (jg == 127) vp = (u16x8)(0);
    union { u16x8 v; u32 d[4]; } um, u0, up;
    um.v = vm; u0.v = v0; up.v = vp;
    f2 P0[4], P1[4], P2[4];
#pragma unroll
    for (int p = 0; p < 4; p++) {
      const f2 xm = bfpair(um.d[p]);
      const f2 x0 = bfpair(u0.d[p]);
      const f2 xp = bfpair(up.d[p]);
      P0[p] = w2[0][0][p] * xm + w2[0][1][p] * x0 + w2[0][2][p] * xp;
      P1[p] = w2[1][0][p] * xm + w2[1][1][p] * x0 + w2[1][2][p] * xp;
      P2[p] = w2[2][0][p] * xm + w2[2][1][p] * x0 + w2[2][2][p] * xp;
    }
    if (r >= 2) {
      const int orow = r0 + r - 2;
      u16x8 ov;
#pragma unroll
      for (int p = 0; p < 4; p++) {
        f2 g2 = accA[p] + P2[p];
        ov[2 * p]     = f2bf(gelu_fast(g2[0]));
        ov[2 * p + 1] = f2bf(gelu_fast(g2[1]));
      }
      *(u16x8*)(dst + (size_t)(ibase + orow * 128 + jg) * 192 + cl) = ov;
    }
#pragma unroll
    for (int p = 0; p < 4; p++) {
      accA[p] = accB[p] + P1[p];
      accB[p] = P0[p];
    }
  }
}

// ---------------- K5: GEMM2 + residual + interleave scatter ----------------
// Epilogue v2: per band (LH/HL/HH), stage f32 tile in LDS (float[128][68],
// stride 68 dw: scatter 2-way max, b128 reads canonical-free), then cooperative
// coalesced residual load (u16x8) + float4 stores of whole 64-ch pixels.
__global__ __launch_bounds__(256) void k5_gemm2(
    const u16* __restrict__ A,     // h2 [2][Mg][192]
    const u16* __restrict__ Bw,    // [192][384]
    const u16* __restrict__ high,  // [NPOS][192]
    float* __restrict__ out,       // [8][256][256][64]
    int chunkStart, int Mg)
{
  __shared__ __align__(16) float smemF[128 * 68];  // 34816 B; As/Bs overlap front
  u16* As = (u16*)smemF;                // 128*32 u16
  u16* Bs = (u16*)smemF + 128 * 32;     // 192*32 u16
  const int t = threadIdx.x;
  const int lane = t & 63, wave = t >> 6;
  const int wm = wave >> 1, wn = wave & 1;
  const int m0 = blockIdx.x * 128;
  const int lrow = lane >> 2, lcol = lane & 3;
  const int frow = lane & 15, fk = (lane >> 4) * 8;

  f4 acc[4][6];
#pragma unroll
  for (int a = 0; a < 4; a++)
#pragma unroll
    for (int b = 0; b < 6; b++) acc[a][b] = 0.0f;

  for (int ks = 0; ks < 12; ++ks) {
    const int kb = ks * 32;
    const u16* Ah = A + (ks >= 6 ? (size_t)Mg * 192 : 0) + (kb - (ks >= 6 ? 192 : 0));
#pragma unroll
    for (int l = 0; l < 2; ++l) {
      const int r = wave * 32 + l * 16 + lrow;
      gl_lds16(Ah + (size_t)(m0 + r) * 192 + lcol * 8, As + (wave * 32 + l * 16) * 32);
    }
#pragma unroll
    for (int l = 0; l < 3; ++l) {
      const int rb = wave * 48 + l * 16 + lrow;
      gl_lds16(Bw + (size_t)rb * 384 + kb + lcol * 8, Bs + (wave * 48 + l * 16) * 32);
    }
    __syncthreads();
    bf8 af[4], bfr[6];
#pragma unroll
    for (int fm = 0; fm < 4; ++fm)
      af[fm] = *(const bf8*)(As + (wm * 64 + fm * 16 + frow) * 32 + fk);
#pragma unroll
    for (int fn = 0; fn < 6; ++fn)
      bfr[fn] = *(const bf8*)(Bs + (wn * 96 + fn * 16 + frow) * 32 + fk);
#pragma unroll
    for (int fm = 0; fm < 4; ++fm)
#pragma unroll
      for (int fn = 0; fn < 6; ++fn)
        acc[fm][fn] = __builtin_amdgcn_mfma_f32_16x16x32_bf16(af[fm], bfr[fn], acc[fm][fn], 0, 0, 0);
    __syncthreads();
  }

  // ---- epilogue v2 ----
  float* Stg = smemF;                    // [128][68] f32
  const int r0 = (lane >> 4) * 4, ccol = lane & 15;
#pragma unroll
  for (int bsel = 0; bsel < 3; ++bsel) {
    if (bsel) __syncthreads();           // previous band's coop reads done
    // scatter this band's acc values into Stg[j][c]
#pragma unroll
    for (int fn = 0; fn < 6; ++fn) {
      const int oc = wn * 96 + fn * 16 + ccol;   // band uniform per wave (wn uniform)
      if ((oc >> 6) == bsel) {
        const int c = oc & 63;
#pragma unroll
        for (int fm = 0; fm < 4; ++fm) {
          const int jb = wm * 64 + fm * 16 + r0;
#pragma unroll
          for (int r = 0; r < 4; ++r)
            Stg[(jb + r) * 68 + c] = acc[fm][fn][r];
        }
      }
    }
    __syncthreads();
    // cooperative: coalesced residual + vector store. 128 rows x 4 thr/row, 2 iters.
    const int p = (bsel + 1) >> 1, q = (bsel + 1) & 1;
#pragma unroll
    for (int it = 0; it < 2; ++it) {
      const int jr = (t >> 2) + it * 64;
      const int cq = (t & 3) * 16;
      const int np = chunkStart + m0 + jr;
      const int bi = np >> 14, rem = np & 16383, ii = rem >> 7;
      const u16* hp = high + (size_t)np * 192 + bsel * 64 + cq;
      union { u16x8 v; u32 d[4]; } h0, h1;
      h0.v = *(const u16x8*)hp;
      h1.v = *(const u16x8*)(hp + 8);
      const float* sp = Stg + jr * 68 + cq;
      f4 o0 = *(const f4*)sp;
      f4 o1 = *(const f4*)(sp + 4);
      f4 o2 = *(const f4*)(sp + 8);
      f4 o3 = *(const f4*)(sp + 12);
      f2 a0 = bfpair(h0.d[0]), a1 = bfpair(h0.d[1]), a2 = bfpair(h0.d[2]), a3 = bfpair(h0.d[3]);
      f2 b0 = bfpair(h1.d[0]), b1 = bfpair(h1.d[1]), b2 = bfpair(h1.d[2]), b3 = bfpair(h1.d[3]);
      o0[0] += a0[0]; o0[1] += a0[1]; o0[2] += a1[0]; o0[3] += a1[1];
      o1[0] += a2[0]; o1[1] += a2[1]; o1[2] += a3[0]; o1[3] += a3[1];
      o2[0] += b0[0]; o2[1] += b0[1]; o2[2] += b1[0]; o2[3] += b1[1];
      o3[0] += b2[0]; o3[1] += b2[1]; o3[2] += b3[0]; o3[3] += b3[1];
      float* op = out + (size_t)(((bi * 256 + 2 * ii + p) * 256) + (2 * jr + q)) * 64 + cq;
      *(f4*)op       = o0;
      *(f4*)(op + 4) = o1;
      *(f4*)(op + 8) = o2;
      *(f4*)(op + 12)= o3;
    }
  }
}

extern "C" void kernel_launch(void* const* d_in, const int* in_sizes, int n_in,
                              void* d_out, int out_size, void* d_ws, size_t ws_size,
                              hipStream_t stream)
{
  const float* x        = (const float*)d_in[0];
  const float* gamma    = (const float*)d_in[1];
  const float* beta     = (const float*)d_in[2];
  const float* w_in     = (const float*)d_in[3];
  const float* w_dw     = (const float*)d_in[4];
  const float* w_out    = (const float*)d_in[5];
  const float* res_scale= (const float*)d_in[6];
  float* out = (float*)d_out;
  char* ws = (char*)d_ws;

  float* stats   = (float*)ws;                     // 384 floats
  float* st      = (float*)(ws + 2048);            // 384 floats
  float* bias1   = (float*)(ws + 4096);            // 384 floats
  u16*   w_in_f  = (u16*)(ws + 8192);              // 147456 B
  u16*   w_out_f = (u16*)(ws + 8192 + 147456);     // 147456 B
  u16*   high    = (u16*)(ws + (size_t)(1 << 19)); // 50331648 B
  const size_t off_h1 = (size_t)(1 << 19) + (size_t)NPOS * 192 * 2;
  const size_t imgBytes = (size_t)16384 * 384 * 2; // per image, both halves
  int G = 8;
  while (G > 1 && off_h1 + 2 * (size_t)G * imgBytes > ws_size) G >>= 1;
  u16* h1 = (u16*)(ws + off_h1);
  u16* h2 = (u16*)(ws + off_h1 + (size_t)G * imgBytes);

  k0_zero<<<1, 384, 0, stream>>>(stats);
  k1_dwt<<<1024, 256, 0, stream>>>(x, high, out, stats);
  k2a<<<1, 256, 0, stream>>>(stats, gamma, beta, st);
  k2b<<<576, 64, 0, stream>>>(w_in, w_out, st, res_scale, w_in_f, bias1, w_out_f);

  for (int cs = 0; cs < 8; cs += G) {
    const int chunkStart = cs * 16384;
    const int Mg = G * 16384;
    k3_gemm1<<<dim3(Mg / 128, 3), 256, 0, stream>>>(high + (size_t)chunkStart * 192, w_in_f, bias1, h1, Mg);
    k4_dw<<<G * 512, 192, 0, stream>>>(h1, w_dw, h2, Mg);
    k5_gemm2<<<dim3(Mg / 128, 1), 256, 0, stream>>>(h2, w_out_f, high, out, chunkStart, Mg);
  }
}

// Round 2
// 412.500 us; speedup vs baseline: 1.0080x; 1.0080x over previous
//
#include <hip/hip_runtime.h>
#include <math.h>

typedef unsigned short u16;
typedef unsigned int u32;
typedef __attribute__((ext_vector_type(4))) float f4;
typedef __attribute__((ext_vector_type(2))) float f2;
typedef __attribute__((ext_vector_type(4))) u16 u16x4;
typedef __attribute__((ext_vector_type(8))) u16 u16x8;
typedef __attribute__((ext_vector_type(8))) short bf8;

#define N_IMG 8
#define HS 128               // half spatial
#define NPOS (N_IMG*HS*HS)   // 131072
#define IN_CH 192
#define HID_CH 384

__device__ __forceinline__ u16 f2bf(float f) {
  union { float f; u32 u; } v; v.f = f;
  u32 r = v.u + 0x7FFFu + ((v.u >> 16) & 1u);
  return (u16)(r >> 16);
}
__device__ __forceinline__ float bf2f(u16 u) {
  union { u32 u; float f; } v; v.u = ((u32)u) << 16; return v.f;
}
// f2 pair from one dword holding two bf16 (even=low half, odd=high half)
__device__ __forceinline__ f2 bfpair(u32 d) {
  union { u32 u; float f; } lo, hi;
  lo.u = d << 16; hi.u = d & 0xffff0000u;
  f2 r; r[0] = lo.f; r[1] = hi.f; return r;
}
// gelu(x) = x * sigmoid(1.595769122x + 0.071354816x^3)  (tanh-form, exact identity)
// = x * rcp(1 + exp2(x*(-2.302208 - 0.102942*x^2)))
__device__ __forceinline__ float gelu_fast(float x) {
  float x2 = x * x;
  float z = x * (-2.302208f - 0.102942f * x2);
  float e = __builtin_amdgcn_exp2f(z);
  return x * __builtin_amdgcn_rcpf(1.0f + e);
}
__device__ __forceinline__ void gl_lds16(const u16* g, u16* l) {
  __builtin_amdgcn_global_load_lds(
      (__attribute__((address_space(1))) void*)(u16*)g,
      (__attribute__((address_space(3))) void*)l, 16, 0, 0);
}

// ---------------- K0: zero stats ----------------
__global__ void k0_zero(float* stats) { stats[threadIdx.x] = 0.0f; }

// ---------------- K1 v2: DWT (interleaved-band semantics) ----------------
// Latency fix: 2048 blocks (j split in halves, 4 iters/thread) + register
// double-buffer prefetch so vmcnt never drains to 0 between iterations.
__global__ __launch_bounds__(256) void k1_dwt(
    const float* __restrict__ x,   // [8][256][256][64]
    u16* __restrict__ high,        // [NPOS][192]
    float* __restrict__ out,       // [8][256][256][64]
    float* __restrict__ stats)     // sum[192], sq[192]
{
  const int blk = blockIdx.x;         // b*256 + i*2 + jh
  const int b = blk >> 8, i = (blk >> 1) & 127, jh = blk & 1;
  const int t = threadIdx.x;
  const int c4 = t & 15;              // input channels c4*4 .. c4*4+3
  const int j0 = t >> 4;              // 0..15
  const int jbase = jh * 64 + j0;
  const int rowE = ((b * 256 + 2 * i) * 256) * 64;
  const int rowO = rowE + 256 * 64;
  const bool isHigh = (c4 >= 4);

  float sacc[16], qacc[16];
#pragma unroll
  for (int v = 0; v < 16; v++) { sacc[v] = 0.f; qacc[v] = 0.f; }

  f4 R[2][4];   // double-buffered {va,vb,vc,vd}
  {
    const int colE = (2 * jbase) * 64 + c4 * 4;
    R[0][0] = *(const f4*)(x + rowE + colE);
    R[0][1] = *(const f4*)(x + rowE + colE + 64);
    R[0][2] = *(const f4*)(x + rowO + colE);
    R[0][3] = *(const f4*)(x + rowO + colE + 64);
  }

#pragma unroll
  for (int iter = 0; iter < 4; ++iter) {
    const int cur = iter & 1, nxt = cur ^ 1;
    if (iter < 3) {
      const int jn = jbase + 16 * (iter + 1);
      const int colE = (2 * jn) * 64 + c4 * 4;
      R[nxt][0] = *(const f4*)(x + rowE + colE);
      R[nxt][1] = *(const f4*)(x + rowE + colE + 64);
      R[nxt][2] = *(const f4*)(x + rowO + colE);
      R[nxt][3] = *(const f4*)(x + rowO + colE + 64);
    }
    const int j = jbase + 16 * iter;
    f4 va = R[cur][0], vb = R[cur][1], vc = R[cur][2], vd = R[cur][3];
    f4 sb0 = (va + vb + vc + vd) * 0.5f;  // LL
    f4 sb1 = (va - vb + vc - vd) * 0.5f;  // LH
    f4 sb2 = (va + vb - vc - vd) * 0.5f;  // HL
    f4 sb3 = (va - vb - vc + vd) * 0.5f;  // HH

    if (!isHigh) {
      float* dst = out + rowE + (2 * j) * 64 + 16 * c4;
#pragma unroll
      for (int cc = 0; cc < 4; cc++) {
        f4 ov;
        ov[0] = sb0[cc]; ov[1] = sb1[cc]; ov[2] = sb2[cc]; ov[3] = sb3[cc];
        ((f4*)dst)[cc] = ov;
      }
    } else {
      const int n = b * 16384 + i * 128 + j;
      u16* dst = high + n * 192 + 16 * (c4 - 4);
#pragma unroll
      for (int half = 0; half < 2; half++) {
        u16x8 pk;
#pragma unroll
        for (int cc2 = 0; cc2 < 2; cc2++) {
          const int cc = half * 2 + cc2;
          pk[cc2 * 4 + 0] = f2bf(sb0[cc]);
          pk[cc2 * 4 + 1] = f2bf(sb1[cc]);
          pk[cc2 * 4 + 2] = f2bf(sb2[cc]);
          pk[cc2 * 4 + 3] = f2bf(sb3[cc]);
        }
        *(u16x8*)(dst + half * 8) = pk;
      }
#pragma unroll
      for (int cc = 0; cc < 4; cc++) {
        float e0 = sb0[cc], e1 = sb1[cc], e2 = sb2[cc], e3 = sb3[cc];
        sacc[cc * 4 + 0] += e0; qacc[cc * 4 + 0] += e0 * e0;
        sacc[cc * 4 + 1] += e1; qacc[cc * 4 + 1] += e1 * e1;
        sacc[cc * 4 + 2] += e2; qacc[cc * 4 + 2] += e2 * e2;
        sacc[cc * 4 + 3] += e3; qacc[cc * 4 + 3] += e3 * e3;
      }
    }
  }

  float vals[32];
#pragma unroll
  for (int v = 0; v < 16; v++) { vals[v] = sacc[v]; vals[16 + v] = qacc[v]; }
#pragma unroll
  for (int v = 0; v < 32; v++) {
    float xx = vals[v];
    xx += __shfl_down(xx, 32);
    xx += __shfl_down(xx, 16);
    vals[v] = xx;
  }
  __shared__ float sred[4][12][32];
  const int lane = t & 63, wave = t >> 6;
  if (lane >= 4 && lane < 16) {
#pragma unroll
    for (int v = 0; v < 32; v++) sred[wave][lane - 4][v] = vals[v];
  }
  __syncthreads();
  if (t < 192) {
    const int g = t >> 4, L = t & 15;
    float s = sred[0][g][L] + sred[1][g][L] + sred[2][g][L] + sred[3][g][L];
    float q = sred[0][g][16 + L] + sred[1][g][16 + L] + sred[2][g][16 + L] + sred[3][g][16 + L];
    atomicAdd(&stats[t], s);
    atomicAdd(&stats[192 + t], q);
  }
}

// ---------------- K2a: BN scale/shift ----------------
__global__ void k2a(const float* __restrict__ stats, const float* __restrict__ gamma,
                    const float* __restrict__ beta, float* __restrict__ st)
{
  const int t = threadIdx.x;
  if (t < 192) {
    const float inv_n = 1.0f / 131072.0f;
    float mean = stats[t] * inv_n;
    float var = stats[192 + t] * inv_n - mean * mean;
    var = fmaxf(var, 0.0f);
    float s = gamma[t] * rsqrtf(var + 1e-5f);
    st[t] = s;
    st[192 + t] = beta[t] - mean * s;
  }
}

// ---------------- K2b: fold weights ----------------
__global__ __launch_bounds__(64) void k2b(
    const float* __restrict__ w_in, const float* __restrict__ w_out,
    const float* __restrict__ st, const float* __restrict__ res_scale,
    u16* __restrict__ w_in_f, float* __restrict__ bias1, u16* __restrict__ w_out_f)
{
  const int o = blockIdx.x, lane = threadIdx.x;
  if (o < 384) {
    float p = 0.f;
    for (int c = lane; c < 192; c += 64) {
      float w = w_in[o * 192 + c];
      w_in_f[o * 192 + c] = f2bf(w * st[c]);
      p += w * st[192 + c];
    }
#pragma unroll
    for (int off = 32; off; off >>= 1) p += __shfl_down(p, off);
    if (lane == 0) bias1[o] = p;
  } else {
    const int o2 = o - 384;
    const float rs = res_scale[0];
    for (int c = lane; c < 384; c += 64)
      w_out_f[o2 * 384 + c] = f2bf(w_out[o2 * 384 + c] * rs);
  }
}

// ---------------- K3: GEMM1  h1 = high @ w_in_f^T + bias ----------------
// h1 layout: [2][Mg][192] (channel halves split)
// Epilogue v2: stage C tile in LDS (u16[128][136], stride 68 dw -> conflict-free),
// then cooperative u16x8 stores (256 B contiguous per row-segment).
__global__ __launch_bounds__(256) void k3_gemm1(
    const u16* __restrict__ A,   // [Mg][192] bf16
    const u16* __restrict__ Bw,  // [384][192] bf16
    const float* __restrict__ bias,
    u16* __restrict__ C,         // [2][Mg][192] bf16
    int Mg)
{
  __shared__ __align__(16) u16 smem[128 * 136];   // 34816 B; As/Bs overlap front
  u16* As = smem;                 // 128*32 u16
  u16* Bs = smem + 128 * 32;      // 128*32 u16
  const int t = threadIdx.x;
  const int lane = t & 63, wave = t >> 6;
  const int wm = wave >> 1, wn = wave & 1;
  const int m0 = blockIdx.x * 128;
  const int n0 = blockIdx.y * 128;
  const int lrow = lane >> 2, lcol = lane & 3;
  const int frow = lane & 15, fk = (lane >> 4) * 8;

  f4 acc[4][4];
#pragma unroll
  for (int a = 0; a < 4; a++)
#pragma unroll
    for (int b = 0; b < 4; b++) acc[a][b] = 0.0f;

  for (int ks = 0; ks < 6; ++ks) {
    const int kb = ks * 32;
#pragma unroll
    for (int l = 0; l < 2; ++l) {
      const int r = wave * 32 + l * 16 + lrow;
      gl_lds16(A + (size_t)(m0 + r) * 192 + kb + lcol * 8, As + (wave * 32 + l * 16) * 32);
      gl_lds16(Bw + (size_t)(n0 + r) * 192 + kb + lcol * 8, Bs + (wave * 32 + l * 16) * 32);
    }
    __syncthreads();
    bf8 af[4], bfr[4];
#pragma unroll
    for (int fm = 0; fm < 4; ++fm)
      af[fm] = *(const bf8*)(As + (wm * 64 + fm * 16 + frow) * 32 + fk);
#pragma unroll
    for (int fn = 0; fn < 4; ++fn)
      bfr[fn] = *(const bf8*)(Bs + (wn * 64 + fn * 16 + frow) * 32 + fk);
#pragma unroll
    for (int fm = 0; fm < 4; ++fm)
#pragma unroll
      for (int fn = 0; fn < 4; ++fn)
        acc[fm][fn] = __builtin_amdgcn_mfma_f32_16x16x32_bf16(af[fm], bfr[fn], acc[fm][fn], 0, 0, 0);
    __syncthreads();
  }

  // -- stage acc -> LDS (bias folded, bf16) --
  u16* Ct = smem;                         // [128][136]
  const int r0 = (lane >> 4) * 4, cc = lane & 15;
#pragma unroll
  for (int fn = 0; fn < 4; ++fn) {
    const int ncol = wn * 64 + fn * 16 + cc;
    const float bv = bias[n0 + ncol];
#pragma unroll
    for (int fm = 0; fm < 4; ++fm) {
      const int mr = wm * 64 + fm * 16 + r0;
#pragma unroll
      for (int r = 0; r < 4; ++r)
        Ct[(mr + r) * 136 + ncol] = f2bf(acc[fm][fn][r] + bv);
    }
  }
  __syncthreads();
  // -- cooperative vector store: 128 rows x 16 segs of 8 ch --
#pragma unroll
  for (int it = 0; it < 8; ++it) {
    const int idx = it * 256 + t;
    const int row = idx >> 4, seg = idx & 15;
    const int col = n0 + seg * 8;
    const int hsel = (col >= 192) ? 1 : 0;
    u16x8 v = *(const u16x8*)(Ct + row * 136 + seg * 8);
    *(u16x8*)(C + (size_t)hsel * Mg * 192 + (size_t)(m0 + row) * 192 + (col - hsel * 192)) = v;
  }
}

// ---------------- K4 v3: depthwise 3x3 + GELU, single-barrier LDS tile ----------------
// h1/h2 layout [2][Mg][192]. Block: 192 thr = 24 ch-octets x 8 j. Tile: 8 rows x 8 j x 192ch(half).
// DMA whole 10-row halo tile to LDS (40 wave-issues), ONE barrier, then pure-LDS compute.
__global__ __launch_bounds__(192) void k4_dw(
    const u16* __restrict__ h1,    // [2][Mg][192]
    const float* __restrict__ wdw, // [384*9]
    u16* __restrict__ h2,          // [2][Mg][192]
    int Mg)
{
  const int bx = blockIdx.x;
  const int half = bx & 1;
  const int jt = (bx >> 1) & 15;
  const int rt = (bx >> 5) & 15;
  const int img = bx >> 9;
  const int t = threadIdx.x;
  const int lane = t & 63, wave = t >> 6;
  const int ibase = img * 16384;
  const int r0 = rt * 8;
  const int jBase = (jt == 0) ? 0 : (jt * 8 - 1);
  const int jOff = (jt == 0) ? 0 : 1;
  const size_t hs = (size_t)half * Mg * 192;
  const u16* src = h1 + hs;
  u16* dst = h2 + hs;

  __shared__ u16 lds[10 * 2048];   // [row 0..9][2048 u16 = 10.67 j * 192ch]

  // bulk DMA: 10 rows x 4 segs of 1024 B
  for (int i = wave; i < 40; i += 3) {
    const int r = i >> 2, seg = i & 3;
    const int gr = r0 - 1 + r;
    if (gr >= 0 && gr < 128) {
      const u16* g = src + (size_t)(ibase + gr * 128 + jBase) * 192 + seg * 512 + lane * 8;
      gl_lds16(g, &lds[r * 2048 + seg * 512]);
    }
  }
  if (rt == 0) {
    for (int c = t; c < 256; c += 192) *(u16x8*)&lds[c * 8] = (u16x8)(0);
  }
  if (rt == 15) {
    for (int c = t; c < 256; c += 192) *(u16x8*)&lds[9 * 2048 + c * 8] = (u16x8)(0);
  }
  __syncthreads();   // the ONLY barrier

  const int o = t % 24, jl = t / 24;
  const int jg = jt * 8 + jl;
  const int cl = o * 8;             // channel offset within half
  const int cg = half * 192 + cl;   // global channel

  f2 w2[3][3][4];
#pragma unroll
  for (int dy = 0; dy < 3; dy++)
#pragma unroll
    for (int dx = 0; dx < 3; dx++)
#pragma unroll
      for (int p = 0; p < 4; p++) {
        w2[dy][dx][p][0] = wdw[(cg + 2 * p) * 9 + dy * 3 + dx];
        w2[dy][dx][p][1] = wdw[(cg + 2 * p + 1) * 9 + dy * 3 + dx];
      }

  int im = jl - 1 + jOff; if (im < 0) im = 0;
  const int i0 = jl + jOff, ip = jl + 1 + jOff;

  f2 accA[4], accB[4];
#pragma unroll
  for (int p = 0; p < 4; p++) { accA[p] = (f2)(0.f); accB[p] = (f2)(0.f); }

#pragma unroll
  for (int r = 0; r < 10; ++r) {
    u16x8 vm = *(const u16x8*)&lds[r * 2048 + im * 192 + cl];
    u16x8 v0 = *(const u16x8*)&lds[r * 2048 + i0 * 192 + cl];
    u16x8 vp = *(const u16x8*)&lds[r * 2048 + ip * 192 + cl];
    if (jg == 0)   vm = (u16x8)(0);
    if (jg == 127) vp = (u16x8)(0);
    union { u16x8 v; u32 d[4]; } um, u0, up;
    um.v = vm; u0.v = v0; up.v = vp;
    f2 P0[4], P1[4], P2[4];
#pragma unroll
    for (int p = 0; p < 4; p++) {
      const f2 xm = bfpair(um.d[p]);
      const f2 x0 = bfpair(u0.d[p]);
      const f2 xp = bfpair(up.d[p]);
      P0[p] = w2[0][0][p] * xm + w2[0][1][p] * x0 + w2[0][2][p] * xp;
      P1[p] = w2[1][0][p] * xm + w2[1][1][p] * x0 + w2[1][2][p] * xp;
      P2[p] = w2[2][0][p] * xm + w2[2][1][p] * x0 + w2[2][2][p] * xp;
    }
    if (r >= 2) {
      const int orow = r0 + r - 2;
      u16x8 ov;
#pragma unroll
      for (int p = 0; p < 4; p++) {
        f2 g2 = accA[p] + P2[p];
        ov[2 * p]     = f2bf(gelu_fast(g2[0]));
        ov[2 * p + 1] = f2bf(gelu_fast(g2[1]));
      }
      *(u16x8*)(dst + (size_t)(ibase + orow * 128 + jg) * 192 + cl) = ov;
    }
#pragma unroll
    for (int p = 0; p < 4; p++) {
      accA[p] = accB[p] + P1[p];
      accB[p] = P0[p];
    }
  }
}

// ---------------- K5: GEMM2 + residual + interleave scatter ----------------
// Epilogue v2: per band (LH/HL/HH), stage f32 tile in LDS (float[128][68],
// stride 68 dw: scatter 2-way max, b128 reads canonical-free), then cooperative
// coalesced residual load (u16x8) + float4 stores of whole 64-ch pixels.
__global__ __launch_bounds__(256) void k5_gemm2(
    const u16* __restrict__ A,     // h2 [2][Mg][192]
    const u16* __restrict__ Bw,    // [192][384]
    const u16* __restrict__ high,  // [NPOS][192]
    float* __restrict__ out,       // [8][256][256][64]
    int chunkStart, int Mg)
{
  __shared__ __align__(16) float smemF[128 * 68];  // 34816 B; As/Bs overlap front
  u16* As = (u16*)smemF;                // 128*32 u16
  u16* Bs = (u16*)smemF + 128 * 32;     // 192*32 u16
  const int t = threadIdx.x;
  const int lane = t & 63, wave = t >> 6;
  const int wm = wave >> 1, wn = wave & 1;
  const int m0 = blockIdx.x * 128;
  const int lrow = lane >> 2, lcol = lane & 3;
  const int frow = lane & 15, fk = (lane >> 4) * 8;

  f4 acc[4][6];
#pragma unroll
  for (int a = 0; a < 4; a++)
#pragma unroll
    for (int b = 0; b < 6; b++) acc[a][b] = 0.0f;

  for (int ks = 0; ks < 12; ++ks) {
    const int kb = ks * 32;
    const u16* Ah = A + (ks >= 6 ? (size_t)Mg * 192 : 0) + (kb - (ks >= 6 ? 192 : 0));
#pragma unroll
    for (int l = 0; l < 2; ++l) {
      const int r = wave * 32 + l * 16 + lrow;
      gl_lds16(Ah + (size_t)(m0 + r) * 192 + lcol * 8, As + (wave * 32 + l * 16) * 32);
    }
#pragma unroll
    for (int l = 0; l < 3; ++l) {
      const int rb = wave * 48 + l * 16 + lrow;
      gl_lds16(Bw + (size_t)rb * 384 + kb + lcol * 8, Bs + (wave * 48 + l * 16) * 32);
    }
    __syncthreads();
    bf8 af[4], bfr[6];
#pragma unroll
    for (int fm = 0; fm < 4; ++fm)
      af[fm] = *(const bf8*)(As + (wm * 64 + fm * 16 + frow) * 32 + fk);
#pragma unroll
    for (int fn = 0; fn < 6; ++fn)
      bfr[fn] = *(const bf8*)(Bs + (wn * 96 + fn * 16 + frow) * 32 + fk);
#pragma unroll
    for (int fm = 0; fm < 4; ++fm)
#pragma unroll
      for (int fn = 0; fn < 6; ++fn)
        acc[fm][fn] = __builtin_amdgcn_mfma_f32_16x16x32_bf16(af[fm], bfr[fn], acc[fm][fn], 0, 0, 0);
    __syncthreads();
  }

  // ---- epilogue v2 ----
  float* Stg = smemF;                    // [128][68] f32
  const int r0 = (lane >> 4) * 4, ccol = lane & 15;
#pragma unroll
  for (int bsel = 0; bsel < 3; ++bsel) {
    if (bsel) __syncthreads();           // previous band's coop reads done
    // scatter this band's acc values into Stg[j][c]
#pragma unroll
    for (int fn = 0; fn < 6; ++fn) {
      const int oc = wn * 96 + fn * 16 + ccol;   // band uniform per wave (wn uniform)
      if ((oc >> 6) == bsel) {
        const int c = oc & 63;
#pragma unroll
        for (int fm = 0; fm < 4; ++fm) {
          const int jb = wm * 64 + fm * 16 + r0;
#pragma unroll
          for (int r = 0; r < 4; ++r)
            Stg[(jb + r) * 68 + c] = acc[fm][fn][r];
        }
      }
    }
    __syncthreads();
    // cooperative: coalesced residual + vector store. 128 rows x 4 thr/row, 2 iters.
    const int p = (bsel + 1) >> 1, q = (bsel + 1) & 1;
#pragma unroll
    for (int it = 0; it < 2; ++it) {
      const int jr = (t >> 2) + it * 64;
      const int cq = (t & 3) * 16;
      const int np = chunkStart + m0 + jr;
      const int bi = np >> 14, rem = np & 16383, ii = rem >> 7;
      const u16* hp = high + (size_t)np * 192 + bsel * 64 + cq;
      union { u16x8 v; u32 d[4]; } h0, h1;
      h0.v = *(const u16x8*)hp;
      h1.v = *(const u16x8*)(hp + 8);
      const float* sp = Stg + jr * 68 + cq;
      f4 o0 = *(const f4*)sp;
      f4 o1 = *(const f4*)(sp + 4);
      f4 o2 = *(const f4*)(sp + 8);
      f4 o3 = *(const f4*)(sp + 12);
      f2 a0 = bfpair(h0.d[0]), a1 = bfpair(h0.d[1]), a2 = bfpair(h0.d[2]), a3 = bfpair(h0.d[3]);
      f2 b0 = bfpair(h1.d[0]), b1 = bfpair(h1.d[1]), b2 = bfpair(h1.d[2]), b3 = bfpair(h1.d[3]);
      o0[0] += a0[0]; o0[1] += a0[1]; o0[2] += a1[0]; o0[3] += a1[1];
      o1[0] += a2[0]; o1[1] += a2[1]; o1[2] += a3[0]; o1[3] += a3[1];
      o2[0] += b0[0]; o2[1] += b0[1]; o2[2] += b1[0]; o2[3] += b1[1];
      o3[0] += b2[0]; o3[1] += b2[1]; o3[2] += b3[0]; o3[3] += b3[1];
      float* op = out + (size_t)(((bi * 256 + 2 * ii + p) * 256) + (2 * jr + q)) * 64 + cq;
      *(f4*)op       = o0;
      *(f4*)(op + 4) = o1;
      *(f4*)(op + 8) = o2;
      *(f4*)(op + 12)= o3;
    }
  }
}

extern "C" void kernel_launch(void* const* d_in, const int* in_sizes, int n_in,
                              void* d_out, int out_size, void* d_ws, size_t ws_size,
                              hipStream_t stream)
{
  const float* x        = (const float*)d_in[0];
  const float* gamma    = (const float*)d_in[1];
  const float* beta     = (const float*)d_in[2];
  const float* w_in     = (const float*)d_in[3];
  const float* w_dw     = (const float*)d_in[4];
  const float* w_out    = (const float*)d_in[5];
  const float* res_scale= (const float*)d_in[6];
  float* out = (float*)d_out;
  char* ws = (char*)d_ws;

  float* stats   = (float*)ws;                     // 384 floats
  float* st      = (float*)(ws + 2048);            // 384 floats
  float* bias1   = (float*)(ws + 4096);            // 384 floats
  u16*   w_in_f  = (u16*)(ws + 8192);              // 147456 B
  u16*   w_out_f = (u16*)(ws + 8192 + 147456);     // 147456 B
  u16*   high    = (u16*)(ws + (size_t)(1 << 19)); // 50331648 B
  const size_t off_h1 = (size_t)(1 << 19) + (size_t)NPOS * 192 * 2;
  const size_t imgBytes = (size_t)16384 * 384 * 2; // per image, both halves
  int G = 8;
  while (G > 1 && off_h1 + 2 * (size_t)G * imgBytes > ws_size) G >>= 1;
  u16* h1 = (u16*)(ws + off_h1);
  u16* h2 = (u16*)(ws + off_h1 + (size_t)G * imgBytes);

  k0_zero<<<1, 384, 0, stream>>>(stats);
  k1_dwt<<<2048, 256, 0, stream>>>(x, high, out, stats);
  k2a<<<1, 256, 0, stream>>>(stats, gamma, beta, st);
  k2b<<<576, 64, 0, stream>>>(w_in, w_out, st, res_scale, w_in_f, bias1, w_out_f);

  for (int cs = 0; cs < 8; cs += G) {
    const int chunkStart = cs * 16384;
    const int Mg = G * 16384;
    k3_gemm1<<<dim3(Mg / 128, 3), 256, 0, stream>>>(high + (size_t)chunkStart * 192, w_in_f, bias1, h1, Mg);
    k4_dw<<<G * 512, 192, 0, stream>>>(h1, w_dw, h2, Mg);
    k5_gemm2<<<dim3(Mg / 128, 1), 256, 0, stream>>>(h2, w_out_f, high, out, chunkStart, Mg);
  }
}

// Round 4
// 400.318 us; speedup vs baseline: 1.0387x; 1.0304x over previous
//
#include <hip/hip_runtime.h>
#include <math.h>

typedef unsigned short u16;
typedef unsigned int u32;
typedef __attribute__((ext_vector_type(4))) float f4;
typedef __attribute__((ext_vector_type(2))) float f2;
typedef __attribute__((ext_vector_type(4))) u16 u16x4;
typedef __attribute__((ext_vector_type(8))) u16 u16x8;
typedef __attribute__((ext_vector_type(8))) short bf8;

#define N_IMG 8
#define HS 128               // half spatial
#define NPOS (N_IMG*HS*HS)   // 131072
#define IN_CH 192
#define HID_CH 384

__device__ __forceinline__ u16 f2bf(float f) {
  union { float f; u32 u; } v; v.f = f;
  u32 r = v.u + 0x7FFFu + ((v.u >> 16) & 1u);
  return (u16)(r >> 16);
}
__device__ __forceinline__ float bf2f(u16 u) {
  union { u32 u; float f; } v; v.u = ((u32)u) << 16; return v.f;
}
// f2 pair from one dword holding two bf16 (even=low half, odd=high half)
__device__ __forceinline__ f2 bfpair(u32 d) {
  union { u32 u; float f; } lo, hi;
  lo.u = d << 16; hi.u = d & 0xffff0000u;
  f2 r; r[0] = lo.f; r[1] = hi.f; return r;
}
// gelu(x) = x * sigmoid(1.595769122x + 0.071354816x^3)  (tanh-form, exact identity)
__device__ __forceinline__ float gelu_fast(float x) {
  float x2 = x * x;
  float z = x * (-2.302208f - 0.102942f * x2);
  float e = __builtin_amdgcn_exp2f(z);
  return x * __builtin_amdgcn_rcpf(1.0f + e);
}
__device__ __forceinline__ void gl_lds16(const u16* g, u16* l) {
  __builtin_amdgcn_global_load_lds(
      (__attribute__((address_space(1))) void*)(u16*)g,
      (__attribute__((address_space(3))) void*)l, 16, 0, 0);
}

// ---------------- K0: zero stats ----------------
__global__ void k0_zero(float* stats) { stats[threadIdx.x] = 0.0f; }

// ---------------- K1 v2: DWT (interleaved-band semantics) ----------------
__global__ __launch_bounds__(256) void k1_dwt(
    const float* __restrict__ x,   // [8][256][256][64]
    u16* __restrict__ high,        // [NPOS][192]
    float* __restrict__ out,       // [8][256][256][64]
    float* __restrict__ stats)     // sum[192], sq[192]
{
  const int blk = blockIdx.x;         // b*256 + i*2 + jh
  const int b = blk >> 8, i = (blk >> 1) & 127, jh = blk & 1;
  const int t = threadIdx.x;
  const int c4 = t & 15;              // input channels c4*4 .. c4*4+3
  const int j0 = t >> 4;              // 0..15
  const int jbase = jh * 64 + j0;
  const int rowE = ((b * 256 + 2 * i) * 256) * 64;
  const int rowO = rowE + 256 * 64;
  const bool isHigh = (c4 >= 4);

  float sacc[16], qacc[16];
#pragma unroll
  for (int v = 0; v < 16; v++) { sacc[v] = 0.f; qacc[v] = 0.f; }

  f4 R[2][4];   // double-buffered {va,vb,vc,vd}
  {
    const int colE = (2 * jbase) * 64 + c4 * 4;
    R[0][0] = *(const f4*)(x + rowE + colE);
    R[0][1] = *(const f4*)(x + rowE + colE + 64);
    R[0][2] = *(const f4*)(x + rowO + colE);
    R[0][3] = *(const f4*)(x + rowO + colE + 64);
  }

#pragma unroll
  for (int iter = 0; iter < 4; ++iter) {
    const int cur = iter & 1, nxt = cur ^ 1;
    if (iter < 3) {
      const int jn = jbase + 16 * (iter + 1);
      const int colE = (2 * jn) * 64 + c4 * 4;
      R[nxt][0] = *(const f4*)(x + rowE + colE);
      R[nxt][1] = *(const f4*)(x + rowE + colE + 64);
      R[nxt][2] = *(const f4*)(x + rowO + colE);
      R[nxt][3] = *(const f4*)(x + rowO + colE + 64);
    }
    const int j = jbase + 16 * iter;
    f4 va = R[cur][0], vb = R[cur][1], vc = R[cur][2], vd = R[cur][3];
    f4 sb0 = (va + vb + vc + vd) * 0.5f;  // LL
    f4 sb1 = (va - vb + vc - vd) * 0.5f;  // LH
    f4 sb2 = (va + vb - vc - vd) * 0.5f;  // HL
    f4 sb3 = (va - vb - vc + vd) * 0.5f;  // HH

    if (!isHigh) {
      float* dst = out + rowE + (2 * j) * 64 + 16 * c4;
#pragma unroll
      for (int cc = 0; cc < 4; cc++) {
        f4 ov;
        ov[0] = sb0[cc]; ov[1] = sb1[cc]; ov[2] = sb2[cc]; ov[3] = sb3[cc];
        ((f4*)dst)[cc] = ov;
      }
    } else {
      const int n = b * 16384 + i * 128 + j;
      u16* dst = high + n * 192 + 16 * (c4 - 4);
#pragma unroll
      for (int half = 0; half < 2; half++) {
        u16x8 pk;
#pragma unroll
        for (int cc2 = 0; cc2 < 2; cc2++) {
          const int cc = half * 2 + cc2;
          pk[cc2 * 4 + 0] = f2bf(sb0[cc]);
          pk[cc2 * 4 + 1] = f2bf(sb1[cc]);
          pk[cc2 * 4 + 2] = f2bf(sb2[cc]);
          pk[cc2 * 4 + 3] = f2bf(sb3[cc]);
        }
        *(u16x8*)(dst + half * 8) = pk;
      }
#pragma unroll
      for (int cc = 0; cc < 4; cc++) {
        float e0 = sb0[cc], e1 = sb1[cc], e2 = sb2[cc], e3 = sb3[cc];
        sacc[cc * 4 + 0] += e0; qacc[cc * 4 + 0] += e0 * e0;
        sacc[cc * 4 + 1] += e1; qacc[cc * 4 + 1] += e1 * e1;
        sacc[cc * 4 + 2] += e2; qacc[cc * 4 + 2] += e2 * e2;
        sacc[cc * 4 + 3] += e3; qacc[cc * 4 + 3] += e3 * e3;
      }
    }
  }

  float vals[32];
#pragma unroll
  for (int v = 0; v < 16; v++) { vals[v] = sacc[v]; vals[16 + v] = qacc[v]; }
#pragma unroll
  for (int v = 0; v < 32; v++) {
    float xx = vals[v];
    xx += __shfl_down(xx, 32);
    xx += __shfl_down(xx, 16);
    vals[v] = xx;
  }
  __shared__ float sred[4][12][32];
  const int lane = t & 63, wave = t >> 6;
  if (lane >= 4 && lane < 16) {
#pragma unroll
    for (int v = 0; v < 32; v++) sred[wave][lane - 4][v] = vals[v];
  }
  __syncthreads();
  if (t < 192) {
    const int g = t >> 4, L = t & 15;
    float s = sred[0][g][L] + sred[1][g][L] + sred[2][g][L] + sred[3][g][L];
    float q = sred[0][g][16 + L] + sred[1][g][16 + L] + sred[2][g][16 + L] + sred[3][g][16 + L];
    atomicAdd(&stats[t], s);
    atomicAdd(&stats[192 + t], q);
  }
}

// ---------------- K2a: BN scale/shift ----------------
__global__ void k2a(const float* __restrict__ stats, const float* __restrict__ gamma,
                    const float* __restrict__ beta, float* __restrict__ st)
{
  const int t = threadIdx.x;
  if (t < 192) {
    const float inv_n = 1.0f / 131072.0f;
    float mean = stats[t] * inv_n;
    float var = stats[192 + t] * inv_n - mean * mean;
    var = fmaxf(var, 0.0f);
    float s = gamma[t] * rsqrtf(var + 1e-5f);
    st[t] = s;
    st[192 + t] = beta[t] - mean * s;
  }
}

// ---------------- K2b: fold weights (+ prepack dw weights [oct][tap][8]) ----------------
__global__ __launch_bounds__(64) void k2b(
    const float* __restrict__ w_in, const float* __restrict__ w_out,
    const float* __restrict__ st, const float* __restrict__ res_scale,
    const float* __restrict__ wdw,
    u16* __restrict__ w_in_f, float* __restrict__ bias1, u16* __restrict__ w_out_f,
    float* __restrict__ wdw_pk)
{
  const int o = blockIdx.x, lane = threadIdx.x;
  if (o < 384) {
    float p = 0.f;
    for (int c = lane; c < 192; c += 64) {
      float w = w_in[o * 192 + c];
      w_in_f[o * 192 + c] = f2bf(w * st[c]);
      p += w * st[192 + c];
    }
#pragma unroll
    for (int off = 32; off; off >>= 1) p += __shfl_down(p, off);
    if (lane == 0) bias1[o] = p;
  } else if (o < 576) {
    const int o2 = o - 384;
    const float rs = res_scale[0];
    for (int c = lane; c < 384; c += 64)
      w_out_f[o2 * 384 + c] = f2bf(w_out[o2 * 384 + c] * rs);
  } else {
    // wdw_pk[oct][tap][e] = wdw[(oct*8+e)*9 + tap], oct=0..47
    // FIX: 72 entries with 64 threads -> strided loop (tap 8 was never written)
    const int oct = o - 576;
    for (int q = lane; q < 72; q += 64) {
      const int tap = q >> 3, e = q & 7;
      wdw_pk[oct * 72 + q] = wdw[(oct * 8 + e) * 9 + tap];
    }
  }
}

// ---------------- K3: GEMM1  h1 = high @ w_in_f^T + bias ----------------
__global__ __launch_bounds__(256) void k3_gemm1(
    const u16* __restrict__ A,   // [Mg][192] bf16
    const u16* __restrict__ Bw,  // [384][192] bf16
    const float* __restrict__ bias,
    u16* __restrict__ C,         // [2][Mg][192] bf16
    int Mg)
{
  __shared__ __align__(16) u16 smem[128 * 136];   // 34816 B; As/Bs overlap front
  u16* As = smem;                 // 128*32 u16
  u16* Bs = smem + 128 * 32;      // 128*32 u16
  const int t = threadIdx.x;
  const int lane = t & 63, wave = t >> 6;
  const int wm = wave >> 1, wn = wave & 1;
  const int m0 = blockIdx.x * 128;
  const int n0 = blockIdx.y * 128;
  const int lrow = lane >> 2, lcol = lane & 3;
  const int frow = lane & 15, fk = (lane >> 4) * 8;

  f4 acc[4][4];
#pragma unroll
  for (int a = 0; a < 4; a++)
#pragma unroll
    for (int b = 0; b < 4; b++) acc[a][b] = 0.0f;

  for (int ks = 0; ks < 6; ++ks) {
    const int kb = ks * 32;
#pragma unroll
    for (int l = 0; l < 2; ++l) {
      const int r = wave * 32 + l * 16 + lrow;
      gl_lds16(A + (size_t)(m0 + r) * 192 + kb + lcol * 8, As + (wave * 32 + l * 16) * 32);
      gl_lds16(Bw + (size_t)(n0 + r) * 192 + kb + lcol * 8, Bs + (wave * 32 + l * 16) * 32);
    }
    __syncthreads();
    bf8 af[4], bfr[4];
#pragma unroll
    for (int fm = 0; fm < 4; ++fm)
      af[fm] = *(const bf8*)(As + (wm * 64 + fm * 16 + frow) * 32 + fk);
#pragma unroll
    for (int fn = 0; fn < 4; ++fn)
      bfr[fn] = *(const bf8*)(Bs + (wn * 64 + fn * 16 + frow) * 32 + fk);
#pragma unroll
    for (int fm = 0; fm < 4; ++fm)
#pragma unroll
      for (int fn = 0; fn < 4; ++fn)
        acc[fm][fn] = __builtin_amdgcn_mfma_f32_16x16x32_bf16(af[fm], bfr[fn], acc[fm][fn], 0, 0, 0);
    __syncthreads();
  }

  // -- stage acc -> LDS (bias folded, bf16) --
  u16* Ct = smem;                         // [128][136]
  const int r0 = (lane >> 4) * 4, cc = lane & 15;
#pragma unroll
  for (int fn = 0; fn < 4; ++fn) {
    const int ncol = wn * 64 + fn * 16 + cc;
    const float bv = bias[n0 + ncol];
#pragma unroll
    for (int fm = 0; fm < 4; ++fm) {
      const int mr = wm * 64 + fm * 16 + r0;
#pragma unroll
      for (int r = 0; r < 4; ++r)
        Ct[(mr + r) * 136 + ncol] = f2bf(acc[fm][fn][r] + bv);
    }
  }
  __syncthreads();
  // -- cooperative vector store: 128 rows x 16 segs of 8 ch --
#pragma unroll
  for (int it = 0; it < 8; ++it) {
    const int idx = it * 256 + t;
    const int row = idx >> 4, seg = idx & 15;
    const int col = n0 + seg * 8;
    const int hsel = (col >= 192) ? 1 : 0;
    u16x8 v = *(const u16x8*)(Ct + row * 136 + seg * 8);
    *(u16x8*)(C + (size_t)hsel * Mg * 192 + (size_t)(m0 + row) * 192 + (col - hsel * 192)) = v;
  }
}

// ---------------- K45: fused depthwise3x3+GELU + GEMM2 + residual + scatter ----------------
// One block = one image row (128 positions). Per K-chunk (32 hid ch):
//   stage h1 rows i-1,i,i+1 (tile [3][128][32]) + B tile -> barrier ->
//   DW+GELU in LDS -> A tile [128][32] -> barrier -> MFMA -> barrier.
// Row halo handled by staging; j halo block-internal (zero at j=0/127).
__global__ __launch_bounds__(256) void k45_dwgemm2(
    const u16* __restrict__ h1,     // [2][Mg][192]
    const float* __restrict__ wdw_pk, // [48][9][8] f32
    const u16* __restrict__ Bw,     // w_out_f [192][384]
    const u16* __restrict__ high,   // [NPOS][192]
    float* __restrict__ out,        // [8][256][256][64]
    int chunkStart, int Mg)
{
  __shared__ __align__(16) char smem_raw[13824 + 45056];
  float* wlds = (float*)smem_raw;                       // 3456 f32
  u16* h1t = (u16*)(smem_raw + 13824);                  // [3][128][32] u16
  u16* Asl = (u16*)(smem_raw + 13824 + 24576);          // [128][32] u16
  u16* Bs  = (u16*)(smem_raw + 13824 + 24576 + 8192);   // [192][32] u16
  float* Stg = (float*)(smem_raw + 13824);              // [128][68] f32 (epilogue)

  const int t = threadIdx.x;
  const int lane = t & 63, wave = t >> 6;
  const int wm = wave >> 1, wn = wave & 1;
  // XCD-chunked bijective swizzle (gridDim.x always % 8 == 0 here)
  const int nwg = gridDim.x;
  const int wg = (blockIdx.x & 7) * (nwg >> 3) + (blockIdx.x >> 3);
  const int img = wg >> 7, irow = wg & 127;
  const int m0 = wg * 128;
  const int lrow = lane >> 2, lcol = lane & 3;
  const int frow = lane & 15, fk = (lane >> 4) * 8;

  // stage dw weights to LDS (once)
  for (int q = t; q < 3456; q += 256) wlds[q] = wdw_pk[q];
  // zero edge halo rows (never DMA'd for edge blocks)
  if (irow == 0) {
    for (int q = t; q < 512; q += 256) *(u16x8*)(h1t + q * 8) = (u16x8)(0);
  }
  if (irow == 127) {
    for (int q = t; q < 512; q += 256) *(u16x8*)(h1t + 2 * 4096 + q * 8) = (u16x8)(0);
  }

  f4 acc[4][6];
#pragma unroll
  for (int a = 0; a < 4; a++)
#pragma unroll
    for (int b = 0; b < 6; b++) acc[a][b] = 0.0f;

  const int oct = t & 3, j0q = t >> 2;   // DW thread mapping: 4 ch-octets x 64 j (x2)

  for (int ks = 0; ks < 12; ++ks) {
    const int kb = ks * 32;
    const int half = (ks >= 6) ? 1 : 0;
    const int klocal = kb - half * 192;
    const u16* hsrc = h1 + (size_t)half * Mg * 192 + klocal;

    // -- stage h1 rows i-1..i+1: 24 wave-issues of 1 KiB --
    for (int is = wave; is < 24; is += 4) {
      const int dy = is >> 3, seg = is & 7;
      const int gr = irow - 1 + dy;
      if (gr >= 0 && gr < 128) {
        const int j = seg * 16 + (lane >> 2);
        gl_lds16(hsrc + (size_t)(img * 16384 + gr * 128 + j) * 192 + (lane & 3) * 8,
                 h1t + (dy * 128 + seg * 16) * 32);
      }
    }
    // -- stage B tile [192][32] --
#pragma unroll
    for (int l = 0; l < 3; ++l) {
      const int rb = wave * 48 + l * 16 + lrow;
      gl_lds16(Bw + (size_t)rb * 384 + kb + lcol * 8, Bs + (wave * 48 + l * 16) * 32);
    }
    __syncthreads();

    // -- DW + GELU: each thread does 8 ch (oct) at j = j0q and j0q+64 --
    f4 w4[9][2];
    {
      const float* wp = wlds + (ks * 4 + oct) * 72;
#pragma unroll
      for (int tap = 0; tap < 9; ++tap) {
        w4[tap][0] = *(const f4*)(wp + tap * 8);
        w4[tap][1] = *(const f4*)(wp + tap * 8 + 4);
      }
    }
#pragma unroll
    for (int jj2 = 0; jj2 < 2; ++jj2) {
      const int jj = j0q + jj2 * 64;
      f2 accd[4];
#pragma unroll
      for (int p = 0; p < 4; p++) accd[p] = (f2)(0.f);
#pragma unroll
      for (int dy = 0; dy < 3; ++dy) {
        const int base = (dy * 128 + jj) * 32 + oct * 8;
        u16x8 xc = *(const u16x8*)(h1t + base);
        u16x8 xl = (jj != 0)   ? *(const u16x8*)(h1t + base - 32) : (u16x8)(0);
        u16x8 xr = (jj != 127) ? *(const u16x8*)(h1t + base + 32) : (u16x8)(0);
        union { u16x8 v; u32 d[4]; } ul, uc, ur;
        ul.v = xl; uc.v = xc; ur.v = xr;
#pragma unroll
        for (int p = 0; p < 4; p++) {
          f2 wl, wc, wr;
          wl[0] = w4[dy * 3 + 0][p >> 1][2 * (p & 1)];
          wl[1] = w4[dy * 3 + 0][p >> 1][2 * (p & 1) + 1];
          wc[0] = w4[dy * 3 + 1][p >> 1][2 * (p & 1)];
          wc[1] = w4[dy * 3 + 1][p >> 1][2 * (p & 1) + 1];
          wr[0] = w4[dy * 3 + 2][p >> 1][2 * (p & 1)];
          wr[1] = w4[dy * 3 + 2][p >> 1][2 * (p & 1) + 1];
          accd[p] += wl * bfpair(ul.d[p]) + wc * bfpair(uc.d[p]) + wr * bfpair(ur.d[p]);
        }
      }
      u16x8 ov;
#pragma unroll
      for (int p = 0; p < 4; p++) {
        ov[2 * p]     = f2bf(gelu_fast(accd[p][0]));
        ov[2 * p + 1] = f2bf(gelu_fast(accd[p][1]));
      }
      *(u16x8*)(Asl + jj * 32 + oct * 8) = ov;
    }
    __syncthreads();

    // -- MFMA --
    bf8 af[4], bfr[6];
#pragma unroll
    for (int fm = 0; fm < 4; ++fm)
      af[fm] = *(const bf8*)(Asl + (wm * 64 + fm * 16 + frow) * 32 + fk);
#pragma unroll
    for (int fn = 0; fn < 6; ++fn)
      bfr[fn] = *(const bf8*)(Bs + (wn * 96 + fn * 16 + frow) * 32 + fk);
#pragma unroll
    for (int fm = 0; fm < 4; ++fm)
#pragma unroll
      for (int fn = 0; fn < 6; ++fn)
        acc[fm][fn] = __builtin_amdgcn_mfma_f32_16x16x32_bf16(af[fm], bfr[fn], acc[fm][fn], 0, 0, 0);
    __syncthreads();
  }

  // ---- epilogue (as K5 v2): per band stage f32 tile, coalesced residual+store ----
  const int r0 = (lane >> 4) * 4, ccol = lane & 15;
#pragma unroll
  for (int bsel = 0; bsel < 3; ++bsel) {
    if (bsel) __syncthreads();
#pragma unroll
    for (int fn = 0; fn < 6; ++fn) {
      const int oc = wn * 96 + fn * 16 + ccol;
      if ((oc >> 6) == bsel) {
        const int c = oc & 63;
#pragma unroll
        for (int fm = 0; fm < 4; ++fm) {
          const int jb = wm * 64 + fm * 16 + r0;
#pragma unroll
          for (int r = 0; r < 4; ++r)
            Stg[(jb + r) * 68 + c] = acc[fm][fn][r];
        }
      }
    }
    __syncthreads();
    const int p = (bsel + 1) >> 1, q = (bsel + 1) & 1;
#pragma unroll
    for (int it = 0; it < 2; ++it) {
      const int jr = (t >> 2) + it * 64;
      const int cq = (t & 3) * 16;
      const int np = chunkStart + m0 + jr;
      const int bi = np >> 14, rem = np & 16383, ii = rem >> 7;
      const u16* hp = high + (size_t)np * 192 + bsel * 64 + cq;
      union { u16x8 v; u32 d[4]; } h0, h1u;
      h0.v = *(const u16x8*)hp;
      h1u.v = *(const u16x8*)(hp + 8);
      const float* sp = Stg + jr * 68 + cq;
      f4 o0 = *(const f4*)sp;
      f4 o1 = *(const f4*)(sp + 4);
      f4 o2 = *(const f4*)(sp + 8);
      f4 o3 = *(const f4*)(sp + 12);
      f2 a0 = bfpair(h0.d[0]), a1 = bfpair(h0.d[1]), a2 = bfpair(h0.d[2]), a3 = bfpair(h0.d[3]);
      f2 b0 = bfpair(h1u.d[0]), b1 = bfpair(h1u.d[1]), b2 = bfpair(h1u.d[2]), b3 = bfpair(h1u.d[3]);
      o0[0] += a0[0]; o0[1] += a0[1]; o0[2] += a1[0]; o0[3] += a1[1];
      o1[0] += a2[0]; o1[1] += a2[1]; o1[2] += a3[0]; o1[3] += a3[1];
      o2[0] += b0[0]; o2[1] += b0[1]; o2[2] += b1[0]; o2[3] += b1[1];
      o3[0] += b2[0]; o3[1] += b2[1]; o3[2] += b3[0]; o3[3] += b3[1];
      float* op = out + (size_t)(((bi * 256 + 2 * ii + p) * 256) + (2 * jr + q)) * 64 + cq;
      *(f4*)op       = o0;
      *(f4*)(op + 4) = o1;
      *(f4*)(op + 8) = o2;
      *(f4*)(op + 12)= o3;
    }
  }
}

extern "C" void kernel_launch(void* const* d_in, const int* in_sizes, int n_in,
                              void* d_out, int out_size, void* d_ws, size_t ws_size,
                              hipStream_t stream)
{
  const float* x        = (const float*)d_in[0];
  const float* gamma    = (const float*)d_in[1];
  const float* beta     = (const float*)d_in[2];
  const float* w_in     = (const float*)d_in[3];
  const float* w_dw     = (const float*)d_in[4];
  const float* w_out    = (const float*)d_in[5];
  const float* res_scale= (const float*)d_in[6];
  float* out = (float*)d_out;
  char* ws = (char*)d_ws;

  float* stats   = (float*)ws;                     // 384 floats
  float* st      = (float*)(ws + 2048);            // 384 floats
  float* bias1   = (float*)(ws + 4096);            // 384 floats
  u16*   w_in_f  = (u16*)(ws + 8192);              // 147456 B
  u16*   w_out_f = (u16*)(ws + 8192 + 147456);     // 147456 B
  float* wdw_pk  = (float*)(ws + 8192 + 2 * 147456); // 13824 B (ends < 2^19)
  u16*   high    = (u16*)(ws + (size_t)(1 << 19)); // 50331648 B
  const size_t off_h1 = (size_t)(1 << 19) + (size_t)NPOS * 192 * 2;
  const size_t imgBytes = (size_t)16384 * 384 * 2; // per image h1 (both halves)
  int G = 8;
  while (G > 1 && off_h1 + (size_t)G * imgBytes > ws_size) G >>= 1;
  u16* h1 = (u16*)(ws + off_h1);

  k0_zero<<<1, 384, 0, stream>>>(stats);
  k1_dwt<<<2048, 256, 0, stream>>>(x, high, out, stats);
  k2a<<<1, 256, 0, stream>>>(stats, gamma, beta, st);
  k2b<<<624, 64, 0, stream>>>(w_in, w_out, st, res_scale, w_dw, w_in_f, bias1, w_out_f, wdw_pk);

  for (int cs = 0; cs < 8; cs += G) {
    const int chunkStart = cs * 16384;
    const int Mg = G * 16384;
    k3_gemm1<<<dim3(Mg / 128, 3), 256, 0, stream>>>(high + (size_t)chunkStart * 192, w_in_f, bias1, h1, Mg);
    k45_dwgemm2<<<G * 128, 256, 0, stream>>>(h1, wdw_pk, w_out_f, high, out, chunkStart, Mg);
  }
}